// Round 37
// baseline (530.728 us; speedup 1.0000x reference)
//
#include <hip/hip_runtime.h>

// ---------------------------------------------------------------------------
// CoSSL round 37: revert to R34 (best, 518us). R36's KC=96 regressed (81us,
// VALU 30%, conflicts 4.7M) — barrier-count theory refuted; L4 is wedged at
// ~75us across 5 structural variants (small per-block work + gather latency).
// Single change vs R34: L4 panel loop issues the B-GATHER before the weight
// staging, so long-latency gathers enter the memory queue first (weights are
// L2-hot and complete underneath). Everything else identical to R34:
// conv1s TH=2 gridx16, cgemmr L2/L3, cgemmi L4 MSPLIT=2 KC=64, bnpool7,
// split-K sref.
// Activations: [p*128+n][c][h][w], p=0 -> q (feats[:,1]), p=1 -> k (feats[:,0]).
// ---------------------------------------------------------------------------

#define NIMG 128
typedef __attribute__((ext_vector_type(8))) short bf16x8;
typedef __attribute__((ext_vector_type(4))) float f32x4;
typedef __attribute__((ext_vector_type(4))) unsigned int u32x4;
typedef unsigned long long ull;

__device__ __forceinline__ unsigned short f2bf(float f) {
  unsigned u = __float_as_uint(f);
  unsigned r = (u + 0x7fffu + ((u >> 16) & 1u)) >> 16;
  return (unsigned short)r;
}
__device__ __forceinline__ float bf2f(unsigned short u) {
  return __uint_as_float((unsigned)u << 16);
}

// ---------------- weight prep ------------------------------------------------
__global__ __launch_bounds__(256) void wtr4_k(
    const float* __restrict__ w2, const float* __restrict__ w3,
    const float* __restrict__ w4, unsigned short* __restrict__ wb2,
    unsigned short* __restrict__ wb3, unsigned short* __restrict__ wb4) {
  const int i = blockIdx.x * 256 + threadIdx.x;
  if (i < 16 * 64) {
    int co = i / 64, k = i % 64;
    int tap = k >> 2, ci = k & 3;
    float v = (k < 36) ? w2[co * 36 + ci * 9 + tap] : 0.f;
    wb2[i] = f2bf(v);
  }
  if (i < 64 * 160) {
    int co = i / 160, k = i % 160;
    int tap = k >> 4, ci = k & 15;
    float v = (k < 144) ? w3[co * 144 + ci * 9 + tap] : 0.f;
    wb3[i] = f2bf(v);
  }
  if (i < 128 * 576) {
    int co = i / 576, k = i % 576;
    int tap = k / 64, ci = k & 63;
    wb4[i] = f2bf(w4[co * 576 + ci * 9 + tap]);
  }
}

// ---------------- L1 conv: 5-row upfront window, TH=2 (Cin=1, Cout=4) -------
__device__ __forceinline__ void l1row(const float* __restrict__ ib, int ih,
                                      int w0i, float* r) {
  if (ih < 0) {
#pragma unroll
    for (int q = 0; q < 9; ++q) r[q] = 0.f;
    return;
  }
  const float* rp = ib + ih * 128 + 2 * w0i;
  const float4 a = *(const float4*)rp;
  const float4 b = *(const float4*)(rp + 4);
  r[0] = (w0i > 0) ? rp[-1] : 0.f;
  r[1] = a.x; r[2] = a.y; r[3] = a.z; r[4] = a.w;
  r[5] = b.x; r[6] = b.y; r[7] = b.z; r[8] = b.w;
}

__global__ __launch_bounds__(256, 4) void conv1s_k(const float* __restrict__ feats,
    const float* __restrict__ w1, const float* __restrict__ b1,
    unsigned short* __restrict__ y, float* __restrict__ part1,
    float* __restrict__ part2) {
  constexpr int TH = 2;
  const int tid = threadIdx.x;
  const int lw = tid & 15, grp = tid >> 4;
  const int h0 = (blockIdx.x * 16 + grp) * TH;   // gridx=16 -> 512 rows
  const int pn = blockIdx.z;
  const int p = pn >> 7, n = pn & 127;
  const int sel = (p == 0) ? 1 : 0;
  const float* ib = feats + (size_t)(n * 2 + sel) * 131072;
  const int w0i = lw * 4;

  float wgt[36];
#pragma unroll
  for (int t = 0; t < 36; ++t) wgt[t] = w1[t];
  float bv[4];
#pragma unroll
  for (int c = 0; c < 4; ++c) bv[c] = b1[c];

  float r[5][9];
#pragma unroll
  for (int j = 0; j < 5; ++j) l1row(ib, 2 * h0 - 1 + j, w0i, r[j]);

  float s1[4] = {0.f, 0.f, 0.f, 0.f}, s2[4] = {0.f, 0.f, 0.f, 0.f};
#pragma unroll
  for (int t = 0; t < TH; ++t) {
    const int h = h0 + t;
    const float* r0 = r[2 * t];
    const float* r1 = r[2 * t + 1];
    const float* r2 = r[2 * t + 2];
#pragma unroll
    for (int co = 0; co < 4; ++co) {
      unsigned short ob[4];
#pragma unroll
      for (int i = 0; i < 4; ++i) {
        float v = bv[co];
#pragma unroll
        for (int kw = 0; kw < 3; ++kw) {
          v = fmaf(wgt[co * 9 + kw],     r0[2 * i + kw], v);
          v = fmaf(wgt[co * 9 + 3 + kw], r1[2 * i + kw], v);
          v = fmaf(wgt[co * 9 + 6 + kw], r2[2 * i + kw], v);
        }
        ob[i] = f2bf(v);
        s1[co] += v; s2[co] += v * v;
      }
      const ull o = (ull)ob[0] | ((ull)ob[1] << 16) | ((ull)ob[2] << 32)
                  | ((ull)ob[3] << 48);
      *(ull*)(y + (((size_t)pn * 4 + co) * 512 + h) * 64 + w0i) = o;
    }
  }
  __shared__ float ws1[4][4], ws2[4][4];
  const int lane = tid & 63, wid = tid >> 6;
#pragma unroll
  for (int co = 0; co < 4; ++co) {
#pragma unroll
    for (int m = 32; m >= 1; m >>= 1) {
      s1[co] += __shfl_xor(s1[co], m);
      s2[co] += __shfl_xor(s2[co], m);
    }
    if (lane == 0) { ws1[wid][co] = s1[co]; ws2[wid][co] = s2[co]; }
  }
  __syncthreads();
  if (tid < 4) {
    const float t1 = ws1[0][tid] + ws1[1][tid] + ws1[2][tid] + ws1[3][tid];
    const float t2 = ws2[0][tid] + ws2[1][tid] + ws2[2][tid] + ws2[3][tid];
    const int nblk = gridDim.x * 128;
    const int blk = (pn & 127) * gridDim.x + blockIdx.x;
    part1[(size_t)(p * 4 + tid) * nblk + blk] = t1;
    part2[(size_t)(p * 4 + tid) * nblk + blk] = t2;
  }
}

// ---------------- helper: 16B bf16x8 load or zero ---------------------------
__device__ __forceinline__ bf16x8 ld16z(const unsigned short* p, bool ok) {
  u32x4 v = *(const u32x4*)p;
  if (!ok) v = (u32x4){0u, 0u, 0u, 0u};
  union { u32x4 a; bf16x8 b; } u; u.a = v; return u.b;
}

// ---------------- LDS-free implicit conv-GEMM (L2/L3: shallow K) ------------
template<int Cin, int H, int W, int M, int SPB, int KP, int WCO, int WSP,
         int Cout, int MSPLIT, int WAVES>
__global__ __launch_bounds__(256, WAVES) void cgemmr_k(
    const unsigned short* __restrict__ x,   // [pn][H][W][Cin] bf16
    const unsigned short* __restrict__ wb,  // [M][KP] bf16
    const float* __restrict__ bias, unsigned short* __restrict__ y,
    float* __restrict__ part1, float* __restrict__ part2) {
  constexpr int Ho = H / 2, Wo = W / 2, HWout = Ho * Wo;
  constexpr int lgWo = (Wo == 8 ? 3 : (Wo == 16 ? 4 : 5));
  constexpr int lgCin = (Cin == 4 ? 2 : (Cin == 16 ? 4 : 6));
  constexpr int MB = M / MSPLIT;
  constexpr int MT = WCO / 16, NT = WSP / 16, KS = KP / 32;
  constexpr int NWN = SPB / WSP;
  __shared__ float ss1[MB], ss2[MB];
  const int tid = threadIdx.x;
  const int pnl = blockIdx.y;
  const int p = pnl >> 7;
  const int spc = blockIdx.x / MSPLIT;
  const int mc = blockIdx.x - spc * MSPLIT;
  const int sp0 = spc * SPB;
  const int m0 = mc * MB;
  const int lane = tid & 63, wid = tid >> 6;
  const int wm = wid / NWN, wn = wid - wm * NWN;
  const int l15 = lane & 15, lg = lane >> 4;
  const unsigned short* xb = x + (size_t)pnl * Cin * (H * W);

  for (int i = tid; i < MB; i += 256) { ss1[i] = 0.f; ss2[i] = 0.f; }
  __syncthreads();

  int ihb[NT], iwb[NT];
#pragma unroll
  for (int nt = 0; nt < NT; ++nt) {
    const int sp = sp0 + wn * WSP + nt * 16 + l15;
    ihb[nt] = 2 * (sp >> lgWo) - 1;
    iwb[nt] = 2 * (sp & (Wo - 1)) - 1;
  }

  f32x4 acc[MT][NT];
#pragma unroll
  for (int mt = 0; mt < MT; ++mt)
#pragma unroll
    for (int nt = 0; nt < NT; ++nt) acc[mt][nt] = (f32x4){0.f, 0.f, 0.f, 0.f};

#pragma unroll
  for (int ks = 0; ks < KS; ++ks) {
    const int kbase = ks * 32 + lg * 8;
    bf16x8 af[MT];
#pragma unroll
    for (int mt = 0; mt < MT; ++mt)
      af[mt] = *(const bf16x8*)(wb + (size_t)(m0 + wm * WCO + mt * 16 + l15) * KP
                                + kbase);
    bf16x8 bfr[NT];
#pragma unroll
    for (int nt = 0; nt < NT; ++nt) {
      if constexpr (Cin >= 8) {
        const int tap = kbase >> lgCin;
        const int ci0 = kbase & (Cin - 1);
        const int kh = tap / 3, kw = tap - kh * 3;
        const int ih = ihb[nt] + kh, iw = iwb[nt] + kw;
        const bool ok = (tap < 9) & ((unsigned)ih < (unsigned)H)
                      & ((unsigned)iw < (unsigned)W);
        const int off = ok ? ((ih * W + iw) * Cin + ci0) : 0;
        bfr[nt] = ld16z(xb + off, ok);
      } else {
        ull hv[2];
#pragma unroll
        for (int hh = 0; hh < 2; ++hh) {
          const int tap = (kbase >> 2) + hh;
          const int kh = tap / 3, kw = tap - kh * 3;
          const int ih = ihb[nt] + kh, iw = iwb[nt] + kw;
          const bool ok = (tap < 9) & ((unsigned)ih < (unsigned)H)
                        & ((unsigned)iw < (unsigned)W);
          const int off = ok ? ((ih * W + iw) * 4) : 0;
          const ull v = *(const ull*)(xb + off);
          hv[hh] = ok ? v : 0ull;
        }
        union { ull u[2]; bf16x8 b; } uu;
        uu.u[0] = hv[0]; uu.u[1] = hv[1];
        bfr[nt] = uu.b;
      }
    }
#pragma unroll
    for (int mt = 0; mt < MT; ++mt)
#pragma unroll
      for (int nt = 0; nt < NT; ++nt)
        acc[mt][nt] = __builtin_amdgcn_mfma_f32_16x16x32_bf16(af[mt], bfr[nt], acc[mt][nt], 0, 0, 0);
  }

  unsigned short* yb = y + (size_t)pnl * Cout * HWout;
#pragma unroll
  for (int mt = 0; mt < MT; ++mt) {
#pragma unroll
    for (int i = 0; i < 4; ++i) {
      const int col = wm * WCO + mt * 16 + lg * 4 + i;   // local co
      const int co = m0 + col;
      const float bv = bias[co];
      float s1 = 0.f, s2 = 0.f;
#pragma unroll
      for (int nt = 0; nt < NT; ++nt) {
        const float v = acc[mt][nt][i] + bv;
        yb[(size_t)co * HWout + sp0 + wn * WSP + nt * 16 + l15] = f2bf(v);
        s1 += v; s2 += v * v;
      }
#pragma unroll
      for (int m = 1; m < 16; m <<= 1) { s1 += __shfl_xor(s1, m); s2 += __shfl_xor(s2, m); }
      if (l15 == 0) {
        atomicAdd(&ss1[col], s1);
        atomicAdd(&ss2[col], s2);
      }
    }
  }
  __syncthreads();
  const int nspc = gridDim.x / MSPLIT;
  const int nblk = nspc * 128;
  const int blkid = (pnl & 127) * nspc + spc;
  for (int i = tid; i < MB; i += 256) {
    part1[(size_t)(p * Cout + m0 + i) * nblk + blkid] = ss1[i];
    part2[(size_t)(p * Cout + m0 + i) * nblk + blkid] = ss2[i];
  }
}

// ---------------- LDS-staged implicit conv-GEMM (L4: deep K) ----------------
template<int Cin, int H, int W, int M, int SPB, int KP, int KC, int WCO, int WSP,
         int Cout, int MSPLIT>
__global__ __launch_bounds__(256) void cgemmi_k(
    const unsigned short* __restrict__ x,   // [pn][H][W][Cin] bf16
    const unsigned short* __restrict__ wb,  // [M][KP] bf16
    const float* __restrict__ bias, unsigned short* __restrict__ y,
    float* __restrict__ part1, float* __restrict__ part2) {
  constexpr int Ho = H / 2, Wo = W / 2, HWout = Ho * Wo;
  constexpr int lgWo = (Wo == 8 ? 3 : (Wo == 16 ? 4 : 5));
  constexpr int lgCin = (Cin == 4 ? 2 : (Cin == 16 ? 4 : 6));
  constexpr int MB = M / MSPLIT;
  constexpr int KCP = KC + 8;
  constexpr int MT = WCO / 16, NT = WSP / 16, KS = KC / 32;
  constexpr int NWN = SPB / WSP;
  constexpr int GR = (Cin < 8) ? 4 : 8;
  __shared__ unsigned short wl[MB][KCP];
  __shared__ unsigned short bl[SPB][KCP];
  __shared__ float ss1[MB], ss2[MB];
  const int tid = threadIdx.x;
  const int pnl = blockIdx.y;
  const int p = pnl >> 7;
  const int spc = blockIdx.x / MSPLIT;
  const int mc = blockIdx.x - spc * MSPLIT;
  const int sp0 = spc * SPB;
  const int m0 = mc * MB;
  const int lane = tid & 63, wid = tid >> 6;
  const int wm = wid / NWN, wn = wid - wm * NWN;
  const int l15 = lane & 15, lg = lane >> 4;
  const unsigned short* xb = x + (size_t)pnl * Cin * (H * W);

  for (int i = tid; i < MB; i += 256) { ss1[i] = 0.f; ss2[i] = 0.f; }

  f32x4 acc[MT][NT];
#pragma unroll
  for (int mt = 0; mt < MT; ++mt)
#pragma unroll
    for (int nt = 0; nt < NT; ++nt) acc[mt][nt] = (f32x4){0.f, 0.f, 0.f, 0.f};

  for (int k0 = 0; k0 < KP; k0 += KC) {
    // B gather FIRST: long-latency HBM/L2 loads enter the queue early
    for (int it = tid; it < SPB * (KC / GR); it += 256) {
      const int row = it / (KC / GR);
      const int rem = it - row * (KC / GR);
      const int k = k0 + rem * GR;
      const int tap = k >> lgCin;
      const int ci0 = k & (Cin - 1);
      const int sp = sp0 + row;
      const int ho = sp >> lgWo, wo = sp & (Wo - 1);
      const int kh = tap / 3, kw = tap - kh * 3;
      const int ih = 2 * ho - 1 + kh, iw = 2 * wo - 1 + kw;
      unsigned short* dst = &bl[row][k - k0];
      if (tap < 9 && (unsigned)ih < (unsigned)H && (unsigned)iw < (unsigned)W) {
        const unsigned short* src = xb + ((size_t)(ih * W + iw) * Cin + ci0);
        if constexpr (GR == 4) {
          *(ull*)dst = *(const ull*)src;       // contiguous 8B
        } else {
          *(u32x4*)dst = *(const u32x4*)src;   // contiguous 16B
        }
      } else {
        *(ull*)dst = 0ull;
        if constexpr (GR == 8) *(ull*)(dst + 4) = 0ull;
      }
    }
    // weights second: L2-hot, complete under the gathers
    for (int it = tid; it < MB * (KC / 8); it += 256) {
      const int row = it / (KC / 8), seg = it - row * (KC / 8);
      const u32x4 v = *(const u32x4*)(wb + (size_t)(m0 + row) * KP + k0 + seg * 8);
      *(u32x4*)(&wl[row][seg * 8]) = v;
    }
    __syncthreads();
#pragma unroll
    for (int ks = 0; ks < KS; ++ks) {
      bf16x8 af[MT], bfr[NT];
#pragma unroll
      for (int mt = 0; mt < MT; ++mt)
        af[mt] = *(const bf16x8*)(&wl[wm * WCO + mt * 16 + l15][ks * 32 + lg * 8]);
#pragma unroll
      for (int nt = 0; nt < NT; ++nt)
        bfr[nt] = *(const bf16x8*)(&bl[wn * WSP + nt * 16 + l15][ks * 32 + lg * 8]);
#pragma unroll
      for (int mt = 0; mt < MT; ++mt)
#pragma unroll
        for (int nt = 0; nt < NT; ++nt)
          acc[mt][nt] = __builtin_amdgcn_mfma_f32_16x16x32_bf16(af[mt], bfr[nt], acc[mt][nt], 0, 0, 0);
    }
    __syncthreads();
  }

  unsigned short* yb = y + (size_t)pnl * Cout * HWout;
#pragma unroll
  for (int mt = 0; mt < MT; ++mt) {
#pragma unroll
    for (int i = 0; i < 4; ++i) {
      const int col = wm * WCO + mt * 16 + lg * 4 + i;   // local co
      const int co = m0 + col;
      const float bv = bias[co];
      float s1 = 0.f, s2 = 0.f;
#pragma unroll
      for (int nt = 0; nt < NT; ++nt) {
        const float v = acc[mt][nt][i] + bv;
        yb[(size_t)co * HWout + sp0 + wn * WSP + nt * 16 + l15] = f2bf(v);
        s1 += v; s2 += v * v;
      }
#pragma unroll
      for (int m = 1; m < 16; m <<= 1) { s1 += __shfl_xor(s1, m); s2 += __shfl_xor(s2, m); }
      if (l15 == 0) {
        atomicAdd(&ss1[col], s1);
        atomicAdd(&ss2[col], s2);
      }
    }
  }
  __syncthreads();
  const int nspc = gridDim.x / MSPLIT;
  const int nblk = nspc * 128;
  const int blkid = (pnl & 127) * nspc + spc;
  for (int i = tid; i < MB; i += 256) {
    part1[(size_t)(p * Cout + m0 + i) * nblk + blkid] = ss1[i];
    part2[(size_t)(p * Cout + m0 + i) * nblk + blkid] = ss2[i];
  }
}

// ---------------- reduce partials -> st (row = blockIdx.x over 2*Cout) ------
__global__ __launch_bounds__(256) void redstat_k(const float* __restrict__ p1,
    const float* __restrict__ p2, float* __restrict__ st, int nblk) {
  const int row = blockIdx.x;
  float s1 = 0.f, s2 = 0.f;
  for (int i = threadIdx.x; i < nblk; i += 256) {
    s1 += p1[(size_t)row * nblk + i];
    s2 += p2[(size_t)row * nblk + i];
  }
  __shared__ float r1[256], r2[256];
  r1[threadIdx.x] = s1; r2[threadIdx.x] = s2;
  __syncthreads();
  for (int stp = 128; stp > 0; stp >>= 1) {
    if (threadIdx.x < stp) {
      r1[threadIdx.x] += r1[threadIdx.x + stp];
      r2[threadIdx.x] += r2[threadIdx.x + stp];
    }
    __syncthreads();
  }
  if (threadIdx.x == 0) {
    st[row] = r1[0];
    st[256 + row] = r2[0];
  }
}

// ---------------- shared pool helper: horizontal sums of relu(a*y+b) --------
template<int W>
__device__ __forceinline__ void row_hs(const unsigned short* __restrict__ yp,
                                       int hh, int H, int w0, float a, float b,
                                       float* hs) {
  if ((unsigned)hh >= (unsigned)H) { hs[0] = hs[1] = hs[2] = hs[3] = 0.f; return; }
  const unsigned short* rp = yp + hh * W;
  const ull B = *(const ull*)(rp + w0);
  float r0 = 0.f, r5 = 0.f;
  if (w0 > 0) r0 = fmaxf(fmaf(a, bf2f(rp[w0 - 1]), b), 0.f);
  if (w0 + 4 < W) r5 = fmaxf(fmaf(a, bf2f(rp[w0 + 4]), b), 0.f);
  const float r1 = fmaxf(fmaf(a, bf2f((unsigned short)(B & 0xffff)), b), 0.f);
  const float r2 = fmaxf(fmaf(a, bf2f((unsigned short)((B >> 16) & 0xffff)), b), 0.f);
  const float r3 = fmaxf(fmaf(a, bf2f((unsigned short)((B >> 32) & 0xffff)), b), 0.f);
  const float r4 = fmaxf(fmaf(a, bf2f((unsigned short)(B >> 48)), b), 0.f);
  hs[0] = r0 + r1 + r2;
  hs[1] = r1 + r2 + r3;
  hs[2] = r2 + r3 + r4;
  hs[3] = r3 + r4 + r5;
}

// ---------------- BN + relu + avgpool, NCHW in -> NHWC out via LDS tile -----
template<int Cout, int H, int W>
__global__ __launch_bounds__(256) void bnpool7_k(const unsigned short* __restrict__ y,
    const float* __restrict__ st, const float* __restrict__ g,
    const float* __restrict__ be, unsigned short* __restrict__ x4, float invCnt) {
  constexpr int W4 = W / 4;
  constexpr int lgW4 = (W4 == 16 ? 4 : (W4 == 8 ? 3 : 2));
  constexpr int NCG = Cout / 4;
  constexpr int lgNCG = (NCG == 1 ? 0 : (NCG == 4 ? 2 : 4));
  constexpr int HQ = 256 >> (lgW4 + lgNCG);
  constexpr int TH = 4;
  constexpr int R = HQ * TH;           // output rows per block
  constexpr int RS = W * Cout;         // shorts per NHWC output row
  constexpr int RSP = RS + 8;          // +16B pad breaks bank alignment
  constexpr int HW = H * W;
  __shared__ unsigned short lbuf[R * RSP];
  const int tid = threadIdx.x;
  const int wq = tid & (W4 - 1);
  const int cg = (tid >> lgW4) & (NCG - 1);
  const int hq = tid >> (lgW4 + lgNCG);
  const int w0 = wq * 4;
  const int c0 = cg * 4;
  const int h0 = blockIdx.x * R;
  const int ht0 = h0 + hq * TH;
  const int pn = blockIdx.z;
  const int p = pn >> 7;

  float a[4], b[4];
#pragma unroll
  for (int j = 0; j < 4; ++j) {
    const int c = c0 + j;
    const float mean = st[p * Cout + c] * invCnt;
    const float var = fmaxf(st[256 + p * Cout + c] * invCnt - mean * mean, 0.f);
    a[j] = g[c] * rsqrtf(var + 1e-5f);
    b[j] = be[c] - mean * a[j];
  }
  const unsigned short* yb = y + (size_t)pn * Cout * (size_t)HW;

  float hsA[4][4], hsB[4][4], hsC[4][4];
#pragma unroll
  for (int j = 0; j < 4; ++j)
    row_hs<W>(yb + (size_t)(c0 + j) * HW, ht0 - 1, H, w0, a[j], b[j], hsA[j]);
#pragma unroll
  for (int j = 0; j < 4; ++j)
    row_hs<W>(yb + (size_t)(c0 + j) * HW, ht0, H, w0, a[j], b[j], hsB[j]);
#pragma unroll
  for (int t = 0; t < TH; ++t) {
    const int h = ht0 + t;
    const int lh = hq * TH + t;
#pragma unroll
    for (int j = 0; j < 4; ++j)
      row_hs<W>(yb + (size_t)(c0 + j) * HW, h + 1, H, w0, a[j], b[j], hsC[j]);
#pragma unroll
    for (int i = 0; i < 4; ++i) {
      unsigned short ob[4];
#pragma unroll
      for (int j = 0; j < 4; ++j)
        ob[j] = f2bf((hsA[j][i] + hsB[j][i] + hsC[j][i]) * (1.f / 9.f));
      const ull o = (ull)ob[0] | ((ull)ob[1] << 16) | ((ull)ob[2] << 32)
                  | ((ull)ob[3] << 48);
      *(ull*)(&lbuf[lh * RSP + (w0 + i) * Cout + c0]) = o;
    }
#pragma unroll
    for (int j = 0; j < 4; ++j)
#pragma unroll
      for (int i = 0; i < 4; ++i) { hsA[j][i] = hsB[j][i]; hsB[j][i] = hsC[j][i]; }
  }
  __syncthreads();
  // flush: block's NHWC region is contiguous -> full-line streaming stores
  unsigned short* xp = x4 + ((size_t)pn * HW + (size_t)h0 * W) * Cout;
  constexpr int SEGS = RS / 8;         // 16B segments per row
  for (int it = tid; it < R * SEGS; it += 256) {
    const int row = it / SEGS, seg = it - row * SEGS;
    const u32x4 v = *(const u32x4*)(&lbuf[row * RSP + seg * 8]);
    *(u32x4*)(xp + (size_t)row * RS + seg * 8) = v;
  }
}

// ---------------- BN + relu + avgpool, NCHW in/out (L4 only) ----------------
template<int Cout, int H, int W, int TH>
__global__ __launch_bounds__(256) void bnpool3_k(const unsigned short* __restrict__ y,
    const float* __restrict__ st, const float* __restrict__ g,
    const float* __restrict__ be, unsigned short* __restrict__ x, float invCnt) {
  constexpr int W4 = W / 4;
  constexpr int GROUPS = 256 / W4;
  constexpr int HW = H * W;
  const int tid = threadIdx.x;
  const int grp = tid / W4, lw = tid - grp * W4;
  const int w0 = lw * 4;
  const int h0 = (blockIdx.x * GROUPS + grp) * TH;
  if (h0 >= H) return;
  const int pn = blockIdx.z, c = blockIdx.y;
  const int p = pn >> 7;
  const float mean = st[p * Cout + c] * invCnt;
  const float var = fmaxf(st[256 + p * Cout + c] * invCnt - mean * mean, 0.f);
  const float a = g[c] * rsqrtf(var + 1e-5f);
  const float b = be[c] - mean * a;
  const unsigned short* yp = y + ((size_t)pn * Cout + c) * (size_t)HW;
  unsigned short* xp = x + ((size_t)pn * Cout + c) * (size_t)HW;

  float hsA[4], hsB[4], hsC[4];
  row_hs<W>(yp, h0 - 1, H, w0, a, b, hsA);
  row_hs<W>(yp, h0, H, w0, a, b, hsB);
#pragma unroll
  for (int t = 0; t < TH; ++t) {
    const int h = h0 + t;
    if (h >= H) break;
    row_hs<W>(yp, h + 1, H, w0, a, b, hsC);
    const ull o = (ull)f2bf((hsA[0] + hsB[0] + hsC[0]) * (1.f / 9.f))
                | ((ull)f2bf((hsA[1] + hsB[1] + hsC[1]) * (1.f / 9.f)) << 16)
                | ((ull)f2bf((hsA[2] + hsB[2] + hsC[2]) * (1.f / 9.f)) << 32)
                | ((ull)f2bf((hsA[3] + hsB[3] + hsC[3]) * (1.f / 9.f)) << 48);
    *(ull*)(xp + h * W + w0) = o;
#pragma unroll
    for (int i = 0; i < 4; ++i) { hsA[i] = hsB[i]; hsB[i] = hsC[i]; }
  }
}

// ---------------- global mean + l2norm (bf16 in); also writes qkT -----------
__global__ __launch_bounds__(256) void feat2_k(const unsigned short* __restrict__ x,
    float* __restrict__ qk, float* __restrict__ qkT) {
  const int pn = blockIdx.x;
  const int tid = threadIdx.x;
  const int lane = tid & 63, wid = tid >> 6;
  __shared__ float fm[128];
  __shared__ float red[128];
  const unsigned short* xb = x + (size_t)pn * 128 * 512;
  for (int c = wid; c < 128; c += 4) {
    const unsigned short* xp = xb + (size_t)c * 512;
    float s = 0.f;
#pragma unroll
    for (int r = 0; r < 4; ++r) {
      const unsigned v = *(const unsigned*)(xp + lane * 2 + r * 128);
      s += bf2f((unsigned short)(v & 0xffff)) + bf2f((unsigned short)(v >> 16));
    }
#pragma unroll
    for (int m = 32; m >= 1; m >>= 1) s += __shfl_xor(s, m);
    if (lane == 0) fm[c] = s * (1.f / 512.f);
  }
  __syncthreads();
  if (tid < 128) red[tid] = fm[tid] * fm[tid];
  __syncthreads();
  for (int step = 64; step > 0; step >>= 1) {
    if (tid < step) red[tid] += red[tid + step];
    __syncthreads();
  }
  const float inv = 1.f / fmaxf(sqrtf(red[0]), 1e-12f);
  if (tid < 128) {
    const float v = fm[tid] * inv;
    qk[(size_t)pn * 128 + tid] = v;
    if (pn < 128) qkT[(size_t)tid * 128 + pn] = v;
  }
}

// ---------------- 1/||ref row|| ---------------------------------------------
__global__ __launch_bounds__(256) void refnorm_k(const float* __restrict__ rf,
    float* __restrict__ rinv) {
  const int n = blockIdx.x;
  float s = 0.f;
  for (int i = threadIdx.x; i < 2304; i += 256) {
    float v = rf[(size_t)n * 2304 + i];
    s += v * v;
  }
  __shared__ float red[256];
  red[threadIdx.x] = s;
  __syncthreads();
  for (int step = 128; step > 0; step >>= 1) {
    if (threadIdx.x < step) red[threadIdx.x] += red[threadIdx.x + step];
    __syncthreads();
  }
  if (threadIdx.x == 0) rinv[n] = 1.f / fmaxf(sqrtf(red[0]), 1e-12f);
}

// ---------------- rfT[k][n] = reff[n][k] * rinv[n] --------------------------
__global__ __launch_bounds__(256) void reft_k(const float* __restrict__ rf,
    const float* __restrict__ rinv, float* __restrict__ rfT) {
  const int flat = blockIdx.x * 256 + threadIdx.x;
  const int n = flat / 2304, k = flat - n * 2304;
  rfT[(size_t)k * 128 + n] = rf[flat] * rinv[n];
}

// ---------------- score_neg = q @ MoCoQueue (8 rows/block) ------------------
__global__ __launch_bounds__(256) void sneg2_k(const float* __restrict__ qkT,
    const float* __restrict__ moco, float* __restrict__ out) {
  const int j = blockIdx.x * 256 + threadIdx.x;
  const int n0 = blockIdx.y * 8;
  float acc[8] = {0.f};
#pragma unroll 4
  for (int k = 0; k < 128; ++k) {
    const float rv = moco[(size_t)k * 2048 + j];
    const float* qp = qkT + (size_t)k * 128 + n0;
#pragma unroll
    for (int i = 0; i < 8; ++i) acc[i] = fmaf(qp[i], rv, acc[i]);
  }
#pragma unroll
  for (int i = 0; i < 8; ++i) out[(size_t)(n0 + i) * 2048 + j] = acc[i];
}

// ---------------- score_ref split-K: partial over k-chunk -------------------
template<int KCH>
__global__ __launch_bounds__(256) void sref3_k(const float* __restrict__ rfT,
    const float* __restrict__ rq, float* __restrict__ part) {
  const int j = blockIdx.x * 256 + threadIdx.x;
  const int n0 = blockIdx.y * 8;
  const int kc = blockIdx.z;
  const int kbeg = kc * KCH;
  float acc[8] = {0.f};
#pragma unroll 4
  for (int k = kbeg; k < kbeg + KCH; ++k) {
    const float rv = rq[(size_t)k * 2048 + j];
    const float* rp = rfT + (size_t)k * 128 + n0;
#pragma unroll
    for (int i = 0; i < 8; ++i) acc[i] = fmaf(rp[i], rv, acc[i]);
  }
  float* pb = part + (size_t)kc * (128 * 2048);
#pragma unroll
  for (int i = 0; i < 8; ++i) pb[(size_t)(n0 + i) * 2048 + j] = acc[i];
}

// ---------------- reduce split-K partials -> SREF ---------------------------
template<int NCH>
__global__ __launch_bounds__(256) void sredr_k(const float* __restrict__ part,
    float* __restrict__ out) {
  const int j = blockIdx.x * 256 + threadIdx.x;
  const int n = blockIdx.y;
  const size_t off = (size_t)n * 2048 + j;
  float s = 0.f;
#pragma unroll
  for (int c = 0; c < NCH; ++c) s += part[(size_t)c * (128 * 2048) + off];
  out[off] = s;
}

// ---------------- top-5 per row of masked score_ref -------------------------
__global__ __launch_bounds__(256) void topk_k(const float* __restrict__ sref,
    const float* __restrict__ iq, const int* __restrict__ idxs,
    int* __restrict__ top) {
  const int n = blockIdx.x;
  const float target = (float)idxs[n];
  float vals[8];
#pragma unroll
  for (int r = 0; r < 8; ++r) {
    const int j = threadIdx.x + r * 256;
    const bool m = (iq[j] == target);
    vals[r] = m ? -__builtin_inff() : sref[(size_t)n * 2048 + j];
  }
  __shared__ float sv[256];
  __shared__ int si[256];
  __shared__ int chosen[5];
  for (int rnd = 0; rnd < 5; ++rnd) {
    float bv = -__builtin_inff();
    int bi = 1 << 30;
#pragma unroll
    for (int r = 0; r < 8; ++r) {
      const int j = threadIdx.x + r * 256;
      bool taken = false;
      for (int t = 0; t < rnd; ++t) taken |= (chosen[t] == j);
      const float v = vals[r];
      if (!taken && (v > bv || (v == bv && j < bi))) { bv = v; bi = j; }
    }
    sv[threadIdx.x] = bv; si[threadIdx.x] = bi;
    __syncthreads();
    for (int step = 128; step > 0; step >>= 1) {
      if (threadIdx.x < step) {
        const float ov = sv[threadIdx.x + step];
        const int oi = si[threadIdx.x + step];
        if (ov > sv[threadIdx.x] || (ov == sv[threadIdx.x] && oi < si[threadIdx.x])) {
          sv[threadIdx.x] = ov; si[threadIdx.x] = oi;
        }
      }
      __syncthreads();
    }
    if (threadIdx.x == 0) chosen[rnd] = si[0];
    __syncthreads();
  }
  if (threadIdx.x < 5) top[n * 5 + threadIdx.x] = chosen[threadIdx.x];
}

// ---------------- score_pos + first columns ---------------------------------
__global__ __launch_bounds__(128) void spos_k(const float* __restrict__ qk,
    float* __restrict__ out) {
  const int n = threadIdx.x;
  float s = 0.f;
  for (int c = 0; c < 128; ++c)
    s = fmaf(qk[(size_t)n * 128 + c], qk[(size_t)(NIMG + n) * 128 + c], s);
  out[(size_t)n * 2049] = s;
  out[(size_t)NIMG * 2049 + (size_t)n * 2049] = 1.f;
}

// ---------------- final assembly --------------------------------------------
__global__ __launch_bounds__(256) void asm_k(const float* __restrict__ sneg,
    const float* __restrict__ sref, const float* __restrict__ iq,
    const int* __restrict__ idxs, const int* __restrict__ top,
    float* __restrict__ out) {
  const int n = blockIdx.y;
  const int j = blockIdx.x * 256 + threadIdx.x;
  const int t0 = top[n * 5 + 0], t1 = top[n * 5 + 1], t2 = top[n * 5 + 2];
  const int t3 = top[n * 5 + 3], t4 = top[n * 5 + 4];
  const float target = (float)idxs[n];
  const bool m = (iq[j] == target);
  const float sr = sref[(size_t)n * 2048 + j];
  const float sr2 = m ? 1.f : sr;
  const bool istop = (j == t0) | (j == t1) | (j == t2) | (j == t3) | (j == t4);
  const float wgt = istop ? 1.f : -1.f;
  out[(size_t)n * 2049 + 1 + j] = sneg[(size_t)n * 2048 + j] * sr2 * wgt;
  const float mf = istop ? 1.f : (m ? 1.f : 0.f);
  out[(size_t)NIMG * 2049 + (size_t)n * 2049 + 1 + j] = mf;
}

// ---------------------------------------------------------------------------
extern "C" void kernel_launch(void* const* d_in, const int* in_sizes, int n_in,
                              void* d_out, int out_size, void* d_ws, size_t ws_size,
                              hipStream_t stream) {
  const float* feats = (const float*)d_in[0];
  const float* reff  = (const float*)d_in[1];
  const int*   idxs  = (const int*)d_in[2];
  const float* moco  = (const float*)d_in[3];
  const float* refq  = (const float*)d_in[4];
  const float* iq    = (const float*)d_in[5];
  const float* w[4]  = {(const float*)d_in[6],  (const float*)d_in[10],
                        (const float*)d_in[14], (const float*)d_in[18]};
  const float* b[4]  = {(const float*)d_in[7],  (const float*)d_in[11],
                        (const float*)d_in[15], (const float*)d_in[19]};
  const float* g[4]  = {(const float*)d_in[8],  (const float*)d_in[12],
                        (const float*)d_in[16], (const float*)d_in[20]};
  const float* be[4] = {(const float*)d_in[9],  (const float*)d_in[13],
                        (const float*)d_in[17], (const float*)d_in[21]};
  float* out = (float*)d_out;

  // workspace layout
  const size_t BIG = 33554432;  // 2*128*131072 elements
  unsigned short* X = (unsigned short*)d_ws;            // BIG bf16 (L4 NCHW out)
  unsigned short* Y = X + BIG;                          // BIG bf16
  float* ST   = (float*)(Y + BIG);  // 4 layers x 512
  unsigned short* WB2 = (unsigned short*)(ST + 2048);   // 16*64
  unsigned short* WB3 = WB2 + 1024;                     // 64*160
  unsigned short* WB4 = WB3 + 10240;                    // 128*576
  float* QK   = (float*)(WB4 + 73728);                  // 2*128*128
  float* QKT  = QK + 32768;         // 128*128
  float* RINV = QKT + 16384;        // 128
  float* RFT  = RINV + 128;         // 2304*128
  float* SNEG = RFT + 294912;       // 128*2048
  float* SREF = SNEG + 262144;      // 128*2048
  int*   TOP  = (int*)(SREF + 262144);                  // 128*5
  float* SPART = (float*)(TOP + 256);                   // 6 x 1M floats
  unsigned short* X4 = (unsigned short*)(SPART + 6 * 128 * 2048);  // 33.5M bf16
  // stats partials alias the (dead-until-head) SNEG area: 2 x 131072 floats
  float* PART1 = SNEG;
  float* PART2 = SNEG + 131072;

  wtr4_k<<<288, 256, 0, stream>>>(w[1], w[2], w[3], WB2, WB3, WB4);

  // ---- layer 1: (1 -> 4), 1024x128 -> 512x64, register conv (TH=2) ---------
  conv1s_k<<<dim3(16, 1, 256), 256, 0, stream>>>(feats, w[0], b[0], Y, PART1, PART2);
  redstat_k<<<8, 256, 0, stream>>>(PART1, PART2, ST, 2048);
  bnpool7_k<4, 512, 64><<<dim3(8, 1, 256), 256, 0, stream>>>(Y, ST, g[0], be[0], X4,
                                                             1.f / (128.f * 32768.f));
  // ---- layer 2: (4 -> 16), LDS-free implicit MFMA (NHWC in) ----------------
  cgemmr_k<4, 512, 64, 16, 256, 64, 16, 64, 16, 1, 6>
      <<<dim3(32, 256), 256, 0, stream>>>(X4, WB2, b[1], Y, PART1, PART2);
  redstat_k<<<32, 256, 0, stream>>>(PART1, PART2, ST + 512, 32 * 128);
  bnpool7_k<16, 256, 32><<<dim3(8, 1, 256), 256, 0, stream>>>(Y, ST + 512, g[1], be[1], X4,
                                                              1.f / (128.f * 8192.f));
  // ---- layer 3: (16 -> 64), LDS-free implicit MFMA (NHWC in) ---------------
  cgemmr_k<16, 256, 32, 64, 256, 160, 64, 64, 64, 1, 3>
      <<<dim3(8, 256), 256, 0, stream>>>(X4, WB3, b[2], Y, PART1, PART2);
  redstat_k<<<128, 256, 0, stream>>>(PART1, PART2, ST + 1024, 8 * 128);
  bnpool7_k<64, 128, 16><<<dim3(8, 1, 256), 256, 0, stream>>>(Y, ST + 1024, g[2], be[2], X4,
                                                              1.f / (128.f * 2048.f));
  // ---- layer 4: (64 -> 128), LDS-staged MFMA, MSPLIT=2, KC=64 --------------
  cgemmi_k<64, 128, 16, 128, 128, 576, 64, 32, 64, 128, 2>
      <<<dim3(8, 256), 256, 0, stream>>>(X4, WB4, b[3], Y, PART1, PART2);
  redstat_k<<<256, 256, 0, stream>>>(PART1, PART2, ST + 1536, 4 * 128);
  bnpool3_k<128, 64, 8, 1><<<dim3(1, 128, 256), 256, 0, stream>>>(Y, ST + 1536, g[3], be[3], X,
                                                                  1.f / (128.f * 512.f));

  // ---- head ----
  feat2_k<<<256, 256, 0, stream>>>(X, QK, QKT);
  refnorm_k<<<128, 256, 0, stream>>>(reff, RINV);
  reft_k<<<1152, 256, 0, stream>>>(reff, RINV, RFT);
  sneg2_k<<<dim3(8, 16), 256, 0, stream>>>(QKT, moco, SNEG);
  sref3_k<384><<<dim3(8, 16, 6), 256, 0, stream>>>(RFT, refq, SPART);
  sredr_k<6><<<dim3(8, 128), 256, 0, stream>>>(SPART, SREF);
  topk_k<<<128, 256, 0, stream>>>(SREF, iq, idxs, TOP);
  spos_k<<<1, 128, 0, stream>>>(QK, out);
  asm_k<<<dim3(8, 128), 256, 0, stream>>>(SNEG, SREF, iq, idxs, TOP, out);
}

// Round 38
// 483.924 us; speedup vs baseline: 1.0967x; 1.0967x over previous
//
#include <hip/hip_runtime.h>

// ---------------------------------------------------------------------------
// CoSSL round 38: R34 config (best, 518us) + L4-tail fusion. bnpool3(L4) +
// feat2 did: read Y -> write X (pooled) -> read X -> channel mean. Mean of
// avgpool is a coverage-weighted sum over Y: cov(h,w)={2,3}x{2,3} windows.
// feat3_k reads Y once (BN+relu+cov fused), reduces, l2norms -> deletes X
// (67MB traffic) and one dispatch. R37's gather-first reorder was neutral ->
// reverted to R34 staging order. Else identical to R34: conv1s TH=2 gridx16,
// cgemmr L2/L3, cgemmi L4 MSPLIT=2 KC=64, bnpool7, split-K sref.
// Activations: [p*128+n][c][h][w], p=0 -> q (feats[:,1]), p=1 -> k (feats[:,0]).
// ---------------------------------------------------------------------------

#define NIMG 128
typedef __attribute__((ext_vector_type(8))) short bf16x8;
typedef __attribute__((ext_vector_type(4))) float f32x4;
typedef __attribute__((ext_vector_type(4))) unsigned int u32x4;
typedef unsigned long long ull;

__device__ __forceinline__ unsigned short f2bf(float f) {
  unsigned u = __float_as_uint(f);
  unsigned r = (u + 0x7fffu + ((u >> 16) & 1u)) >> 16;
  return (unsigned short)r;
}
__device__ __forceinline__ float bf2f(unsigned short u) {
  return __uint_as_float((unsigned)u << 16);
}

// ---------------- weight prep ------------------------------------------------
__global__ __launch_bounds__(256) void wtr4_k(
    const float* __restrict__ w2, const float* __restrict__ w3,
    const float* __restrict__ w4, unsigned short* __restrict__ wb2,
    unsigned short* __restrict__ wb3, unsigned short* __restrict__ wb4) {
  const int i = blockIdx.x * 256 + threadIdx.x;
  if (i < 16 * 64) {
    int co = i / 64, k = i % 64;
    int tap = k >> 2, ci = k & 3;
    float v = (k < 36) ? w2[co * 36 + ci * 9 + tap] : 0.f;
    wb2[i] = f2bf(v);
  }
  if (i < 64 * 160) {
    int co = i / 160, k = i % 160;
    int tap = k >> 4, ci = k & 15;
    float v = (k < 144) ? w3[co * 144 + ci * 9 + tap] : 0.f;
    wb3[i] = f2bf(v);
  }
  if (i < 128 * 576) {
    int co = i / 576, k = i % 576;
    int tap = k / 64, ci = k & 63;
    wb4[i] = f2bf(w4[co * 576 + ci * 9 + tap]);
  }
}

// ---------------- L1 conv: 5-row upfront window, TH=2 (Cin=1, Cout=4) -------
__device__ __forceinline__ void l1row(const float* __restrict__ ib, int ih,
                                      int w0i, float* r) {
  if (ih < 0) {
#pragma unroll
    for (int q = 0; q < 9; ++q) r[q] = 0.f;
    return;
  }
  const float* rp = ib + ih * 128 + 2 * w0i;
  const float4 a = *(const float4*)rp;
  const float4 b = *(const float4*)(rp + 4);
  r[0] = (w0i > 0) ? rp[-1] : 0.f;
  r[1] = a.x; r[2] = a.y; r[3] = a.z; r[4] = a.w;
  r[5] = b.x; r[6] = b.y; r[7] = b.z; r[8] = b.w;
}

__global__ __launch_bounds__(256, 4) void conv1s_k(const float* __restrict__ feats,
    const float* __restrict__ w1, const float* __restrict__ b1,
    unsigned short* __restrict__ y, float* __restrict__ part1,
    float* __restrict__ part2) {
  constexpr int TH = 2;
  const int tid = threadIdx.x;
  const int lw = tid & 15, grp = tid >> 4;
  const int h0 = (blockIdx.x * 16 + grp) * TH;   // gridx=16 -> 512 rows
  const int pn = blockIdx.z;
  const int p = pn >> 7, n = pn & 127;
  const int sel = (p == 0) ? 1 : 0;
  const float* ib = feats + (size_t)(n * 2 + sel) * 131072;
  const int w0i = lw * 4;

  float wgt[36];
#pragma unroll
  for (int t = 0; t < 36; ++t) wgt[t] = w1[t];
  float bv[4];
#pragma unroll
  for (int c = 0; c < 4; ++c) bv[c] = b1[c];

  float r[5][9];
#pragma unroll
  for (int j = 0; j < 5; ++j) l1row(ib, 2 * h0 - 1 + j, w0i, r[j]);

  float s1[4] = {0.f, 0.f, 0.f, 0.f}, s2[4] = {0.f, 0.f, 0.f, 0.f};
#pragma unroll
  for (int t = 0; t < TH; ++t) {
    const int h = h0 + t;
    const float* r0 = r[2 * t];
    const float* r1 = r[2 * t + 1];
    const float* r2 = r[2 * t + 2];
#pragma unroll
    for (int co = 0; co < 4; ++co) {
      unsigned short ob[4];
#pragma unroll
      for (int i = 0; i < 4; ++i) {
        float v = bv[co];
#pragma unroll
        for (int kw = 0; kw < 3; ++kw) {
          v = fmaf(wgt[co * 9 + kw],     r0[2 * i + kw], v);
          v = fmaf(wgt[co * 9 + 3 + kw], r1[2 * i + kw], v);
          v = fmaf(wgt[co * 9 + 6 + kw], r2[2 * i + kw], v);
        }
        ob[i] = f2bf(v);
        s1[co] += v; s2[co] += v * v;
      }
      const ull o = (ull)ob[0] | ((ull)ob[1] << 16) | ((ull)ob[2] << 32)
                  | ((ull)ob[3] << 48);
      *(ull*)(y + (((size_t)pn * 4 + co) * 512 + h) * 64 + w0i) = o;
    }
  }
  __shared__ float ws1[4][4], ws2[4][4];
  const int lane = tid & 63, wid = tid >> 6;
#pragma unroll
  for (int co = 0; co < 4; ++co) {
#pragma unroll
    for (int m = 32; m >= 1; m >>= 1) {
      s1[co] += __shfl_xor(s1[co], m);
      s2[co] += __shfl_xor(s2[co], m);
    }
    if (lane == 0) { ws1[wid][co] = s1[co]; ws2[wid][co] = s2[co]; }
  }
  __syncthreads();
  if (tid < 4) {
    const float t1 = ws1[0][tid] + ws1[1][tid] + ws1[2][tid] + ws1[3][tid];
    const float t2 = ws2[0][tid] + ws2[1][tid] + ws2[2][tid] + ws2[3][tid];
    const int nblk = gridDim.x * 128;
    const int blk = (pn & 127) * gridDim.x + blockIdx.x;
    part1[(size_t)(p * 4 + tid) * nblk + blk] = t1;
    part2[(size_t)(p * 4 + tid) * nblk + blk] = t2;
  }
}

// ---------------- helper: 16B bf16x8 load or zero ---------------------------
__device__ __forceinline__ bf16x8 ld16z(const unsigned short* p, bool ok) {
  u32x4 v = *(const u32x4*)p;
  if (!ok) v = (u32x4){0u, 0u, 0u, 0u};
  union { u32x4 a; bf16x8 b; } u; u.a = v; return u.b;
}

// ---------------- LDS-free implicit conv-GEMM (L2/L3: shallow K) ------------
template<int Cin, int H, int W, int M, int SPB, int KP, int WCO, int WSP,
         int Cout, int MSPLIT, int WAVES>
__global__ __launch_bounds__(256, WAVES) void cgemmr_k(
    const unsigned short* __restrict__ x,   // [pn][H][W][Cin] bf16
    const unsigned short* __restrict__ wb,  // [M][KP] bf16
    const float* __restrict__ bias, unsigned short* __restrict__ y,
    float* __restrict__ part1, float* __restrict__ part2) {
  constexpr int Ho = H / 2, Wo = W / 2, HWout = Ho * Wo;
  constexpr int lgWo = (Wo == 8 ? 3 : (Wo == 16 ? 4 : 5));
  constexpr int lgCin = (Cin == 4 ? 2 : (Cin == 16 ? 4 : 6));
  constexpr int MB = M / MSPLIT;
  constexpr int MT = WCO / 16, NT = WSP / 16, KS = KP / 32;
  constexpr int NWN = SPB / WSP;
  __shared__ float ss1[MB], ss2[MB];
  const int tid = threadIdx.x;
  const int pnl = blockIdx.y;
  const int p = pnl >> 7;
  const int spc = blockIdx.x / MSPLIT;
  const int mc = blockIdx.x - spc * MSPLIT;
  const int sp0 = spc * SPB;
  const int m0 = mc * MB;
  const int lane = tid & 63, wid = tid >> 6;
  const int wm = wid / NWN, wn = wid - wm * NWN;
  const int l15 = lane & 15, lg = lane >> 4;
  const unsigned short* xb = x + (size_t)pnl * Cin * (H * W);

  for (int i = tid; i < MB; i += 256) { ss1[i] = 0.f; ss2[i] = 0.f; }
  __syncthreads();

  int ihb[NT], iwb[NT];
#pragma unroll
  for (int nt = 0; nt < NT; ++nt) {
    const int sp = sp0 + wn * WSP + nt * 16 + l15;
    ihb[nt] = 2 * (sp >> lgWo) - 1;
    iwb[nt] = 2 * (sp & (Wo - 1)) - 1;
  }

  f32x4 acc[MT][NT];
#pragma unroll
  for (int mt = 0; mt < MT; ++mt)
#pragma unroll
    for (int nt = 0; nt < NT; ++nt) acc[mt][nt] = (f32x4){0.f, 0.f, 0.f, 0.f};

#pragma unroll
  for (int ks = 0; ks < KS; ++ks) {
    const int kbase = ks * 32 + lg * 8;
    bf16x8 af[MT];
#pragma unroll
    for (int mt = 0; mt < MT; ++mt)
      af[mt] = *(const bf16x8*)(wb + (size_t)(m0 + wm * WCO + mt * 16 + l15) * KP
                                + kbase);
    bf16x8 bfr[NT];
#pragma unroll
    for (int nt = 0; nt < NT; ++nt) {
      if constexpr (Cin >= 8) {
        const int tap = kbase >> lgCin;
        const int ci0 = kbase & (Cin - 1);
        const int kh = tap / 3, kw = tap - kh * 3;
        const int ih = ihb[nt] + kh, iw = iwb[nt] + kw;
        const bool ok = (tap < 9) & ((unsigned)ih < (unsigned)H)
                      & ((unsigned)iw < (unsigned)W);
        const int off = ok ? ((ih * W + iw) * Cin + ci0) : 0;
        bfr[nt] = ld16z(xb + off, ok);
      } else {
        ull hv[2];
#pragma unroll
        for (int hh = 0; hh < 2; ++hh) {
          const int tap = (kbase >> 2) + hh;
          const int kh = tap / 3, kw = tap - kh * 3;
          const int ih = ihb[nt] + kh, iw = iwb[nt] + kw;
          const bool ok = (tap < 9) & ((unsigned)ih < (unsigned)H)
                        & ((unsigned)iw < (unsigned)W);
          const int off = ok ? ((ih * W + iw) * 4) : 0;
          const ull v = *(const ull*)(xb + off);
          hv[hh] = ok ? v : 0ull;
        }
        union { ull u[2]; bf16x8 b; } uu;
        uu.u[0] = hv[0]; uu.u[1] = hv[1];
        bfr[nt] = uu.b;
      }
    }
#pragma unroll
    for (int mt = 0; mt < MT; ++mt)
#pragma unroll
      for (int nt = 0; nt < NT; ++nt)
        acc[mt][nt] = __builtin_amdgcn_mfma_f32_16x16x32_bf16(af[mt], bfr[nt], acc[mt][nt], 0, 0, 0);
  }

  unsigned short* yb = y + (size_t)pnl * Cout * HWout;
#pragma unroll
  for (int mt = 0; mt < MT; ++mt) {
#pragma unroll
    for (int i = 0; i < 4; ++i) {
      const int col = wm * WCO + mt * 16 + lg * 4 + i;   // local co
      const int co = m0 + col;
      const float bv = bias[co];
      float s1 = 0.f, s2 = 0.f;
#pragma unroll
      for (int nt = 0; nt < NT; ++nt) {
        const float v = acc[mt][nt][i] + bv;
        yb[(size_t)co * HWout + sp0 + wn * WSP + nt * 16 + l15] = f2bf(v);
        s1 += v; s2 += v * v;
      }
#pragma unroll
      for (int m = 1; m < 16; m <<= 1) { s1 += __shfl_xor(s1, m); s2 += __shfl_xor(s2, m); }
      if (l15 == 0) {
        atomicAdd(&ss1[col], s1);
        atomicAdd(&ss2[col], s2);
      }
    }
  }
  __syncthreads();
  const int nspc = gridDim.x / MSPLIT;
  const int nblk = nspc * 128;
  const int blkid = (pnl & 127) * nspc + spc;
  for (int i = tid; i < MB; i += 256) {
    part1[(size_t)(p * Cout + m0 + i) * nblk + blkid] = ss1[i];
    part2[(size_t)(p * Cout + m0 + i) * nblk + blkid] = ss2[i];
  }
}

// ---------------- LDS-staged implicit conv-GEMM (L4: deep K) ----------------
template<int Cin, int H, int W, int M, int SPB, int KP, int KC, int WCO, int WSP,
         int Cout, int MSPLIT>
__global__ __launch_bounds__(256) void cgemmi_k(
    const unsigned short* __restrict__ x,   // [pn][H][W][Cin] bf16
    const unsigned short* __restrict__ wb,  // [M][KP] bf16
    const float* __restrict__ bias, unsigned short* __restrict__ y,
    float* __restrict__ part1, float* __restrict__ part2) {
  constexpr int Ho = H / 2, Wo = W / 2, HWout = Ho * Wo;
  constexpr int lgWo = (Wo == 8 ? 3 : (Wo == 16 ? 4 : 5));
  constexpr int lgCin = (Cin == 4 ? 2 : (Cin == 16 ? 4 : 6));
  constexpr int MB = M / MSPLIT;
  constexpr int KCP = KC + 8;
  constexpr int MT = WCO / 16, NT = WSP / 16, KS = KC / 32;
  constexpr int NWN = SPB / WSP;
  constexpr int GR = (Cin < 8) ? 4 : 8;
  __shared__ unsigned short wl[MB][KCP];
  __shared__ unsigned short bl[SPB][KCP];
  __shared__ float ss1[MB], ss2[MB];
  const int tid = threadIdx.x;
  const int pnl = blockIdx.y;
  const int p = pnl >> 7;
  const int spc = blockIdx.x / MSPLIT;
  const int mc = blockIdx.x - spc * MSPLIT;
  const int sp0 = spc * SPB;
  const int m0 = mc * MB;
  const int lane = tid & 63, wid = tid >> 6;
  const int wm = wid / NWN, wn = wid - wm * NWN;
  const int l15 = lane & 15, lg = lane >> 4;
  const unsigned short* xb = x + (size_t)pnl * Cin * (H * W);

  for (int i = tid; i < MB; i += 256) { ss1[i] = 0.f; ss2[i] = 0.f; }

  f32x4 acc[MT][NT];
#pragma unroll
  for (int mt = 0; mt < MT; ++mt)
#pragma unroll
    for (int nt = 0; nt < NT; ++nt) acc[mt][nt] = (f32x4){0.f, 0.f, 0.f, 0.f};

  for (int k0 = 0; k0 < KP; k0 += KC) {
    for (int it = tid; it < MB * (KC / 8); it += 256) {
      const int row = it / (KC / 8), seg = it - row * (KC / 8);
      const u32x4 v = *(const u32x4*)(wb + (size_t)(m0 + row) * KP + k0 + seg * 8);
      *(u32x4*)(&wl[row][seg * 8]) = v;
    }
    for (int it = tid; it < SPB * (KC / GR); it += 256) {
      const int row = it / (KC / GR);
      const int rem = it - row * (KC / GR);
      const int k = k0 + rem * GR;
      const int tap = k >> lgCin;
      const int ci0 = k & (Cin - 1);
      const int sp = sp0 + row;
      const int ho = sp >> lgWo, wo = sp & (Wo - 1);
      const int kh = tap / 3, kw = tap - kh * 3;
      const int ih = 2 * ho - 1 + kh, iw = 2 * wo - 1 + kw;
      unsigned short* dst = &bl[row][k - k0];
      if (tap < 9 && (unsigned)ih < (unsigned)H && (unsigned)iw < (unsigned)W) {
        const unsigned short* src = xb + ((size_t)(ih * W + iw) * Cin + ci0);
        if constexpr (GR == 4) {
          *(ull*)dst = *(const ull*)src;       // contiguous 8B
        } else {
          *(u32x4*)dst = *(const u32x4*)src;   // contiguous 16B
        }
      } else {
        *(ull*)dst = 0ull;
        if constexpr (GR == 8) *(ull*)(dst + 4) = 0ull;
      }
    }
    __syncthreads();
#pragma unroll
    for (int ks = 0; ks < KS; ++ks) {
      bf16x8 af[MT], bfr[NT];
#pragma unroll
      for (int mt = 0; mt < MT; ++mt)
        af[mt] = *(const bf16x8*)(&wl[wm * WCO + mt * 16 + l15][ks * 32 + lg * 8]);
#pragma unroll
      for (int nt = 0; nt < NT; ++nt)
        bfr[nt] = *(const bf16x8*)(&bl[wn * WSP + nt * 16 + l15][ks * 32 + lg * 8]);
#pragma unroll
      for (int mt = 0; mt < MT; ++mt)
#pragma unroll
        for (int nt = 0; nt < NT; ++nt)
          acc[mt][nt] = __builtin_amdgcn_mfma_f32_16x16x32_bf16(af[mt], bfr[nt], acc[mt][nt], 0, 0, 0);
    }
    __syncthreads();
  }

  unsigned short* yb = y + (size_t)pnl * Cout * HWout;
#pragma unroll
  for (int mt = 0; mt < MT; ++mt) {
#pragma unroll
    for (int i = 0; i < 4; ++i) {
      const int col = wm * WCO + mt * 16 + lg * 4 + i;   // local co
      const int co = m0 + col;
      const float bv = bias[co];
      float s1 = 0.f, s2 = 0.f;
#pragma unroll
      for (int nt = 0; nt < NT; ++nt) {
        const float v = acc[mt][nt][i] + bv;
        yb[(size_t)co * HWout + sp0 + wn * WSP + nt * 16 + l15] = f2bf(v);
        s1 += v; s2 += v * v;
      }
#pragma unroll
      for (int m = 1; m < 16; m <<= 1) { s1 += __shfl_xor(s1, m); s2 += __shfl_xor(s2, m); }
      if (l15 == 0) {
        atomicAdd(&ss1[col], s1);
        atomicAdd(&ss2[col], s2);
      }
    }
  }
  __syncthreads();
  const int nspc = gridDim.x / MSPLIT;
  const int nblk = nspc * 128;
  const int blkid = (pnl & 127) * nspc + spc;
  for (int i = tid; i < MB; i += 256) {
    part1[(size_t)(p * Cout + m0 + i) * nblk + blkid] = ss1[i];
    part2[(size_t)(p * Cout + m0 + i) * nblk + blkid] = ss2[i];
  }
}

// ---------------- reduce partials -> st (row = blockIdx.x over 2*Cout) ------
__global__ __launch_bounds__(256) void redstat_k(const float* __restrict__ p1,
    const float* __restrict__ p2, float* __restrict__ st, int nblk) {
  const int row = blockIdx.x;
  float s1 = 0.f, s2 = 0.f;
  for (int i = threadIdx.x; i < nblk; i += 256) {
    s1 += p1[(size_t)row * nblk + i];
    s2 += p2[(size_t)row * nblk + i];
  }
  __shared__ float r1[256], r2[256];
  r1[threadIdx.x] = s1; r2[threadIdx.x] = s2;
  __syncthreads();
  for (int stp = 128; stp > 0; stp >>= 1) {
    if (threadIdx.x < stp) {
      r1[threadIdx.x] += r1[threadIdx.x + stp];
      r2[threadIdx.x] += r2[threadIdx.x + stp];
    }
    __syncthreads();
  }
  if (threadIdx.x == 0) {
    st[row] = r1[0];
    st[256 + row] = r2[0];
  }
}

// ---------------- shared pool helper: horizontal sums of relu(a*y+b) --------
template<int W>
__device__ __forceinline__ void row_hs(const unsigned short* __restrict__ yp,
                                       int hh, int H, int w0, float a, float b,
                                       float* hs) {
  if ((unsigned)hh >= (unsigned)H) { hs[0] = hs[1] = hs[2] = hs[3] = 0.f; return; }
  const unsigned short* rp = yp + hh * W;
  const ull B = *(const ull*)(rp + w0);
  float r0 = 0.f, r5 = 0.f;
  if (w0 > 0) r0 = fmaxf(fmaf(a, bf2f(rp[w0 - 1]), b), 0.f);
  if (w0 + 4 < W) r5 = fmaxf(fmaf(a, bf2f(rp[w0 + 4]), b), 0.f);
  const float r1 = fmaxf(fmaf(a, bf2f((unsigned short)(B & 0xffff)), b), 0.f);
  const float r2 = fmaxf(fmaf(a, bf2f((unsigned short)((B >> 16) & 0xffff)), b), 0.f);
  const float r3 = fmaxf(fmaf(a, bf2f((unsigned short)((B >> 32) & 0xffff)), b), 0.f);
  const float r4 = fmaxf(fmaf(a, bf2f((unsigned short)(B >> 48)), b), 0.f);
  hs[0] = r0 + r1 + r2;
  hs[1] = r1 + r2 + r3;
  hs[2] = r2 + r3 + r4;
  hs[3] = r3 + r4 + r5;
}

// ---------------- BN + relu + avgpool, NCHW in -> NHWC out via LDS tile -----
template<int Cout, int H, int W>
__global__ __launch_bounds__(256) void bnpool7_k(const unsigned short* __restrict__ y,
    const float* __restrict__ st, const float* __restrict__ g,
    const float* __restrict__ be, unsigned short* __restrict__ x4, float invCnt) {
  constexpr int W4 = W / 4;
  constexpr int lgW4 = (W4 == 16 ? 4 : (W4 == 8 ? 3 : 2));
  constexpr int NCG = Cout / 4;
  constexpr int lgNCG = (NCG == 1 ? 0 : (NCG == 4 ? 2 : 4));
  constexpr int HQ = 256 >> (lgW4 + lgNCG);
  constexpr int TH = 4;
  constexpr int R = HQ * TH;           // output rows per block
  constexpr int RS = W * Cout;         // shorts per NHWC output row
  constexpr int RSP = RS + 8;          // +16B pad breaks bank alignment
  constexpr int HW = H * W;
  __shared__ unsigned short lbuf[R * RSP];
  const int tid = threadIdx.x;
  const int wq = tid & (W4 - 1);
  const int cg = (tid >> lgW4) & (NCG - 1);
  const int hq = tid >> (lgW4 + lgNCG);
  const int w0 = wq * 4;
  const int c0 = cg * 4;
  const int h0 = blockIdx.x * R;
  const int ht0 = h0 + hq * TH;
  const int pn = blockIdx.z;
  const int p = pn >> 7;

  float a[4], b[4];
#pragma unroll
  for (int j = 0; j < 4; ++j) {
    const int c = c0 + j;
    const float mean = st[p * Cout + c] * invCnt;
    const float var = fmaxf(st[256 + p * Cout + c] * invCnt - mean * mean, 0.f);
    a[j] = g[c] * rsqrtf(var + 1e-5f);
    b[j] = be[c] - mean * a[j];
  }
  const unsigned short* yb = y + (size_t)pn * Cout * (size_t)HW;

  float hsA[4][4], hsB[4][4], hsC[4][4];
#pragma unroll
  for (int j = 0; j < 4; ++j)
    row_hs<W>(yb + (size_t)(c0 + j) * HW, ht0 - 1, H, w0, a[j], b[j], hsA[j]);
#pragma unroll
  for (int j = 0; j < 4; ++j)
    row_hs<W>(yb + (size_t)(c0 + j) * HW, ht0, H, w0, a[j], b[j], hsB[j]);
#pragma unroll
  for (int t = 0; t < TH; ++t) {
    const int h = ht0 + t;
    const int lh = hq * TH + t;
#pragma unroll
    for (int j = 0; j < 4; ++j)
      row_hs<W>(yb + (size_t)(c0 + j) * HW, h + 1, H, w0, a[j], b[j], hsC[j]);
#pragma unroll
    for (int i = 0; i < 4; ++i) {
      unsigned short ob[4];
#pragma unroll
      for (int j = 0; j < 4; ++j)
        ob[j] = f2bf((hsA[j][i] + hsB[j][i] + hsC[j][i]) * (1.f / 9.f));
      const ull o = (ull)ob[0] | ((ull)ob[1] << 16) | ((ull)ob[2] << 32)
                  | ((ull)ob[3] << 48);
      *(ull*)(&lbuf[lh * RSP + (w0 + i) * Cout + c0]) = o;
    }
#pragma unroll
    for (int j = 0; j < 4; ++j)
#pragma unroll
      for (int i = 0; i < 4; ++i) { hsA[j][i] = hsB[j][i]; hsB[j][i] = hsC[j][i]; }
  }
  __syncthreads();
  // flush: block's NHWC region is contiguous -> full-line streaming stores
  unsigned short* xp = x4 + ((size_t)pn * HW + (size_t)h0 * W) * Cout;
  constexpr int SEGS = RS / 8;         // 16B segments per row
  for (int it = tid; it < R * SEGS; it += 256) {
    const int row = it / SEGS, seg = it - row * SEGS;
    const u32x4 v = *(const u32x4*)(&lbuf[row * RSP + seg * 8]);
    *(u32x4*)(xp + (size_t)row * RS + seg * 8) = v;
  }
}

// ---------------- fused L4 BN+relu+avgpool-mean + l2norm (replaces bnpool3+feat2)
// mean_c of avgpool(relu(bn(y))) = sum_hw relu(a*y+b)*cov(h,w) / (9*512),
// cov = (#3x3 windows covering pixel) = {2,3}x{2,3} border/interior.
__global__ __launch_bounds__(256) void feat3_k(const unsigned short* __restrict__ y,
    const float* __restrict__ st, const float* __restrict__ g,
    const float* __restrict__ be, float* __restrict__ qk, float* __restrict__ qkT) {
  const int pn = blockIdx.x;
  const int p = pn >> 7;
  const int tid = threadIdx.x;
  const int lane = tid & 63, wid = tid >> 6;
  __shared__ float fm[128];
  __shared__ float red[128];
  const unsigned short* yb = y + (size_t)pn * 128 * 512;
  const float invCnt = 1.f / (128.f * 512.f);
  for (int c = wid; c < 128; c += 4) {
    const float mean = st[p * 128 + c] * invCnt;
    const float var = fmaxf(st[256 + p * 128 + c] * invCnt - mean * mean, 0.f);
    const float a = g[c] * rsqrtf(var + 1e-5f);
    const float b = be[c] - mean * a;
    const unsigned short* yp = yb + (size_t)c * 512;
    float s = 0.f;
#pragma unroll
    for (int r = 0; r < 4; ++r) {
      const int pos0 = lane * 2 + r * 128;
      const unsigned v = *(const unsigned*)(yp + pos0);
#pragma unroll
      for (int e = 0; e < 2; ++e) {
        const int pos = pos0 + e;
        const int h = pos >> 3, w = pos & 7;   // H=64, W=8
        const float cov = ((h == 0 || h == 63) ? 2.f : 3.f)
                        * ((w == 0 || w == 7) ? 2.f : 3.f);
        const unsigned short u = (e == 0) ? (unsigned short)(v & 0xffff)
                                          : (unsigned short)(v >> 16);
        s += fmaxf(fmaf(a, bf2f(u), b), 0.f) * cov;
      }
    }
#pragma unroll
    for (int m = 32; m >= 1; m >>= 1) s += __shfl_xor(s, m);
    if (lane == 0) fm[c] = s * (1.f / (9.f * 512.f));
  }
  __syncthreads();
  if (tid < 128) red[tid] = fm[tid] * fm[tid];
  __syncthreads();
  for (int step = 64; step > 0; step >>= 1) {
    if (tid < step) red[tid] += red[tid + step];
    __syncthreads();
  }
  const float inv = 1.f / fmaxf(sqrtf(red[0]), 1e-12f);
  if (tid < 128) {
    const float v = fm[tid] * inv;
    qk[(size_t)pn * 128 + tid] = v;
    if (pn < 128) qkT[(size_t)tid * 128 + pn] = v;
  }
}

// ---------------- 1/||ref row|| ---------------------------------------------
__global__ __launch_bounds__(256) void refnorm_k(const float* __restrict__ rf,
    float* __restrict__ rinv) {
  const int n = blockIdx.x;
  float s = 0.f;
  for (int i = threadIdx.x; i < 2304; i += 256) {
    float v = rf[(size_t)n * 2304 + i];
    s += v * v;
  }
  __shared__ float red[256];
  red[threadIdx.x] = s;
  __syncthreads();
  for (int step = 128; step > 0; step >>= 1) {
    if (threadIdx.x < step) red[threadIdx.x] += red[threadIdx.x + step];
    __syncthreads();
  }
  if (threadIdx.x == 0) rinv[n] = 1.f / fmaxf(sqrtf(red[0]), 1e-12f);
}

// ---------------- rfT[k][n] = reff[n][k] * rinv[n] --------------------------
__global__ __launch_bounds__(256) void reft_k(const float* __restrict__ rf,
    const float* __restrict__ rinv, float* __restrict__ rfT) {
  const int flat = blockIdx.x * 256 + threadIdx.x;
  const int n = flat / 2304, k = flat - n * 2304;
  rfT[(size_t)k * 128 + n] = rf[flat] * rinv[n];
}

// ---------------- score_neg = q @ MoCoQueue (8 rows/block) ------------------
__global__ __launch_bounds__(256) void sneg2_k(const float* __restrict__ qkT,
    const float* __restrict__ moco, float* __restrict__ out) {
  const int j = blockIdx.x * 256 + threadIdx.x;
  const int n0 = blockIdx.y * 8;
  float acc[8] = {0.f};
#pragma unroll 4
  for (int k = 0; k < 128; ++k) {
    const float rv = moco[(size_t)k * 2048 + j];
    const float* qp = qkT + (size_t)k * 128 + n0;
#pragma unroll
    for (int i = 0; i < 8; ++i) acc[i] = fmaf(qp[i], rv, acc[i]);
  }
#pragma unroll
  for (int i = 0; i < 8; ++i) out[(size_t)(n0 + i) * 2048 + j] = acc[i];
}

// ---------------- score_ref split-K: partial over k-chunk -------------------
template<int KCH>
__global__ __launch_bounds__(256) void sref3_k(const float* __restrict__ rfT,
    const float* __restrict__ rq, float* __restrict__ part) {
  const int j = blockIdx.x * 256 + threadIdx.x;
  const int n0 = blockIdx.y * 8;
  const int kc = blockIdx.z;
  const int kbeg = kc * KCH;
  float acc[8] = {0.f};
#pragma unroll 4
  for (int k = kbeg; k < kbeg + KCH; ++k) {
    const float rv = rq[(size_t)k * 2048 + j];
    const float* rp = rfT + (size_t)k * 128 + n0;
#pragma unroll
    for (int i = 0; i < 8; ++i) acc[i] = fmaf(rp[i], rv, acc[i]);
  }
  float* pb = part + (size_t)kc * (128 * 2048);
#pragma unroll
  for (int i = 0; i < 8; ++i) pb[(size_t)(n0 + i) * 2048 + j] = acc[i];
}

// ---------------- reduce split-K partials -> SREF ---------------------------
template<int NCH>
__global__ __launch_bounds__(256) void sredr_k(const float* __restrict__ part,
    float* __restrict__ out) {
  const int j = blockIdx.x * 256 + threadIdx.x;
  const int n = blockIdx.y;
  const size_t off = (size_t)n * 2048 + j;
  float s = 0.f;
#pragma unroll
  for (int c = 0; c < NCH; ++c) s += part[(size_t)c * (128 * 2048) + off];
  out[off] = s;
}

// ---------------- top-5 per row of masked score_ref -------------------------
__global__ __launch_bounds__(256) void topk_k(const float* __restrict__ sref,
    const float* __restrict__ iq, const int* __restrict__ idxs,
    int* __restrict__ top) {
  const int n = blockIdx.x;
  const float target = (float)idxs[n];
  float vals[8];
#pragma unroll
  for (int r = 0; r < 8; ++r) {
    const int j = threadIdx.x + r * 256;
    const bool m = (iq[j] == target);
    vals[r] = m ? -__builtin_inff() : sref[(size_t)n * 2048 + j];
  }
  __shared__ float sv[256];
  __shared__ int si[256];
  __shared__ int chosen[5];
  for (int rnd = 0; rnd < 5; ++rnd) {
    float bv = -__builtin_inff();
    int bi = 1 << 30;
#pragma unroll
    for (int r = 0; r < 8; ++r) {
      const int j = threadIdx.x + r * 256;
      bool taken = false;
      for (int t = 0; t < rnd; ++t) taken |= (chosen[t] == j);
      const float v = vals[r];
      if (!taken && (v > bv || (v == bv && j < bi))) { bv = v; bi = j; }
    }
    sv[threadIdx.x] = bv; si[threadIdx.x] = bi;
    __syncthreads();
    for (int step = 128; step > 0; step >>= 1) {
      if (threadIdx.x < step) {
        const float ov = sv[threadIdx.x + step];
        const int oi = si[threadIdx.x + step];
        if (ov > sv[threadIdx.x] || (ov == sv[threadIdx.x] && oi < si[threadIdx.x])) {
          sv[threadIdx.x] = ov; si[threadIdx.x] = oi;
        }
      }
      __syncthreads();
    }
    if (threadIdx.x == 0) chosen[rnd] = si[0];
    __syncthreads();
  }
  if (threadIdx.x < 5) top[n * 5 + threadIdx.x] = chosen[threadIdx.x];
}

// ---------------- score_pos + first columns ---------------------------------
__global__ __launch_bounds__(128) void spos_k(const float* __restrict__ qk,
    float* __restrict__ out) {
  const int n = threadIdx.x;
  float s = 0.f;
  for (int c = 0; c < 128; ++c)
    s = fmaf(qk[(size_t)n * 128 + c], qk[(size_t)(NIMG + n) * 128 + c], s);
  out[(size_t)n * 2049] = s;
  out[(size_t)NIMG * 2049 + (size_t)n * 2049] = 1.f;
}

// ---------------- final assembly --------------------------------------------
__global__ __launch_bounds__(256) void asm_k(const float* __restrict__ sneg,
    const float* __restrict__ sref, const float* __restrict__ iq,
    const int* __restrict__ idxs, const int* __restrict__ top,
    float* __restrict__ out) {
  const int n = blockIdx.y;
  const int j = blockIdx.x * 256 + threadIdx.x;
  const int t0 = top[n * 5 + 0], t1 = top[n * 5 + 1], t2 = top[n * 5 + 2];
  const int t3 = top[n * 5 + 3], t4 = top[n * 5 + 4];
  const float target = (float)idxs[n];
  const bool m = (iq[j] == target);
  const float sr = sref[(size_t)n * 2048 + j];
  const float sr2 = m ? 1.f : sr;
  const bool istop = (j == t0) | (j == t1) | (j == t2) | (j == t3) | (j == t4);
  const float wgt = istop ? 1.f : -1.f;
  out[(size_t)n * 2049 + 1 + j] = sneg[(size_t)n * 2048 + j] * sr2 * wgt;
  const float mf = istop ? 1.f : (m ? 1.f : 0.f);
  out[(size_t)NIMG * 2049 + (size_t)n * 2049 + 1 + j] = mf;
}

// ---------------------------------------------------------------------------
extern "C" void kernel_launch(void* const* d_in, const int* in_sizes, int n_in,
                              void* d_out, int out_size, void* d_ws, size_t ws_size,
                              hipStream_t stream) {
  const float* feats = (const float*)d_in[0];
  const float* reff  = (const float*)d_in[1];
  const int*   idxs  = (const int*)d_in[2];
  const float* moco  = (const float*)d_in[3];
  const float* refq  = (const float*)d_in[4];
  const float* iq    = (const float*)d_in[5];
  const float* w[4]  = {(const float*)d_in[6],  (const float*)d_in[10],
                        (const float*)d_in[14], (const float*)d_in[18]};
  const float* b[4]  = {(const float*)d_in[7],  (const float*)d_in[11],
                        (const float*)d_in[15], (const float*)d_in[19]};
  const float* g[4]  = {(const float*)d_in[8],  (const float*)d_in[12],
                        (const float*)d_in[16], (const float*)d_in[20]};
  const float* be[4] = {(const float*)d_in[9],  (const float*)d_in[13],
                        (const float*)d_in[17], (const float*)d_in[21]};
  float* out = (float*)d_out;

  // workspace layout
  const size_t BIG = 33554432;  // 2*128*131072 elements
  unsigned short* X = (unsigned short*)d_ws;            // BIG bf16 (unused now)
  unsigned short* Y = X + BIG;                          // BIG bf16
  float* ST   = (float*)(Y + BIG);  // 4 layers x 512
  unsigned short* WB2 = (unsigned short*)(ST + 2048);   // 16*64
  unsigned short* WB3 = WB2 + 1024;                     // 64*160
  unsigned short* WB4 = WB3 + 10240;                    // 128*576
  float* QK   = (float*)(WB4 + 73728);                  // 2*128*128
  float* QKT  = QK + 32768;         // 128*128
  float* RINV = QKT + 16384;        // 128
  float* RFT  = RINV + 128;         // 2304*128
  float* SNEG = RFT + 294912;       // 128*2048
  float* SREF = SNEG + 262144;      // 128*2048
  int*   TOP  = (int*)(SREF + 262144);                  // 128*5
  float* SPART = (float*)(TOP + 256);                   // 6 x 1M floats
  unsigned short* X4 = (unsigned short*)(SPART + 6 * 128 * 2048);  // 33.5M bf16
  // stats partials alias the (dead-until-head) SNEG area: 2 x 131072 floats
  float* PART1 = SNEG;
  float* PART2 = SNEG + 131072;

  wtr4_k<<<288, 256, 0, stream>>>(w[1], w[2], w[3], WB2, WB3, WB4);

  // ---- layer 1: (1 -> 4), 1024x128 -> 512x64, register conv (TH=2) ---------
  conv1s_k<<<dim3(16, 1, 256), 256, 0, stream>>>(feats, w[0], b[0], Y, PART1, PART2);
  redstat_k<<<8, 256, 0, stream>>>(PART1, PART2, ST, 2048);
  bnpool7_k<4, 512, 64><<<dim3(8, 1, 256), 256, 0, stream>>>(Y, ST, g[0], be[0], X4,
                                                             1.f / (128.f * 32768.f));
  // ---- layer 2: (4 -> 16), LDS-free implicit MFMA (NHWC in) ----------------
  cgemmr_k<4, 512, 64, 16, 256, 64, 16, 64, 16, 1, 6>
      <<<dim3(32, 256), 256, 0, stream>>>(X4, WB2, b[1], Y, PART1, PART2);
  redstat_k<<<32, 256, 0, stream>>>(PART1, PART2, ST + 512, 32 * 128);
  bnpool7_k<16, 256, 32><<<dim3(8, 1, 256), 256, 0, stream>>>(Y, ST + 512, g[1], be[1], X4,
                                                              1.f / (128.f * 8192.f));
  // ---- layer 3: (16 -> 64), LDS-free implicit MFMA (NHWC in) ---------------
  cgemmr_k<16, 256, 32, 64, 256, 160, 64, 64, 64, 1, 3>
      <<<dim3(8, 256), 256, 0, stream>>>(X4, WB3, b[2], Y, PART1, PART2);
  redstat_k<<<128, 256, 0, stream>>>(PART1, PART2, ST + 1024, 8 * 128);
  bnpool7_k<64, 128, 16><<<dim3(8, 1, 256), 256, 0, stream>>>(Y, ST + 1024, g[2], be[2], X4,
                                                              1.f / (128.f * 2048.f));
  // ---- layer 4: (64 -> 128), LDS-staged MFMA, MSPLIT=2, KC=64 --------------
  cgemmi_k<64, 128, 16, 128, 128, 576, 64, 32, 64, 128, 2>
      <<<dim3(8, 256), 256, 0, stream>>>(X4, WB4, b[3], Y, PART1, PART2);
  redstat_k<<<256, 256, 0, stream>>>(PART1, PART2, ST + 1536, 4 * 128);

  // ---- head: fused L4 BN+pool-mean+l2norm, then scores ----------------------
  feat3_k<<<256, 256, 0, stream>>>(Y, ST + 1536, g[3], be[3], QK, QKT);
  refnorm_k<<<128, 256, 0, stream>>>(reff, RINV);
  reft_k<<<1152, 256, 0, stream>>>(reff, RINV, RFT);
  sneg2_k<<<dim3(8, 16), 256, 0, stream>>>(QKT, moco, SNEG);
  sref3_k<384><<<dim3(8, 16, 6), 256, 0, stream>>>(RFT, refq, SPART);
  sredr_k<6><<<dim3(8, 128), 256, 0, stream>>>(SPART, SREF);
  topk_k<<<128, 256, 0, stream>>>(SREF, iq, idxs, TOP);
  spos_k<<<1, 128, 0, stream>>>(QK, out);
  asm_k<<<dim3(8, 128), 256, 0, stream>>>(SNEG, SREF, iq, idxs, TOP, out);
}